// Round 1
// baseline (1491.492 us; speedup 1.0000x reference)
//
#include <hip/hip_runtime.h>

// Problem constants: B=4, C=256 (concat of two 128s), H=W=64, 9 taps, 18 offset ch.
constexpr int N_PIX   = 4 * 64 * 64;      // 16384 pixels (b,h,w)
constexpr int KDIM    = 256 * 9;          // 2304 GEMM K
constexpr int FEAT_N  = N_PIX * 256;      // 4,194,304 floats per feat buffer
constexpr int OFF_N   = N_PIX * 18;       // 294,912
constexpr int WT_L    = KDIM * 256;       // 589,824 per deform layer
constexpr int WTO_L   = KDIM * 18;        // 41,472 per offset layer

// ---------------- concat [x;y] NCHW -> feat NHWC ----------------
__global__ __launch_bounds__(256) void concat_nhwc(const float* __restrict__ x,
                                                   const float* __restrict__ y,
                                                   float* __restrict__ feat) {
  __shared__ float tile[64][65];
  int bid = blockIdx.x;                 // b*256 + h*4 + ct
  int ct = bid & 3, h = (bid >> 2) & 63, b = bid >> 8;
  int c0 = ct * 64;
  const float* src = (c0 < 128) ? x : y;
  int cs = c0 & 127;
  int t = threadIdx.x;
  int w = t & 63, cl = t >> 6;
#pragma unroll
  for (int i = 0; i < 16; ++i) {
    int c = cl + i * 4;
    tile[c][w] = src[((b * 128 + cs + c) * 64 + h) * 64 + w];
  }
  __syncthreads();
  int c2 = t & 63, wl = t >> 6;
#pragma unroll
  for (int i = 0; i < 16; ++i) {
    int w2 = wl + i * 4;
    feat[((b * 64 + h) * 64 + w2) * 256 + c0 + c2] = tile[c2][w2];
  }
}

// ---------------- weight transposes (one-time) ----------------
// deform_w [3][256(o)][256(i)][3][3] -> wt[l][(tap*256+i)*256 + o]
__global__ __launch_bounds__(256) void t_dw(const float* __restrict__ dw,
                                            float* __restrict__ wt) {
  int g = blockIdx.x * 256 + threadIdx.x;      // < 3*589824
  int l = g / WT_L, r = g % WT_L;
  int o = r & 255, k = r >> 8;
  int i = k & 255, tap = k >> 8;
  wt[g] = dw[(l * 256 + o) * KDIM + i * 9 + tap];
}

// offset_w [4][18(o)][256(i)][3][3] -> wto[l][(tap*256+i)*18 + o]
__global__ __launch_bounds__(256) void t_ow(const float* __restrict__ ow,
                                            float* __restrict__ wto) {
  int g = blockIdx.x * 256 + threadIdx.x;      // < 4*41472
  int l = g / WTO_L, r = g % WTO_L;
  int o = r % 18, k = r / 18;
  int i = k & 255, tap = k >> 8;
  wto[g] = ow[(l * 18 + o) * KDIM + i * 9 + tap];
}

// ---------------- offset conv (3x3 SAME, 256 -> 18) ----------------
// One thread per pixel, 4-way K split across the 4 waves of a block.
// NCHW=false: write off[p*18+o] (NHWC-ish); true: write [b][o][h][w] to d_out.
template <bool NCHW>
__global__ __launch_bounds__(256) void off_conv(const float* __restrict__ feat,
                                                const float* __restrict__ wo,
                                                float* __restrict__ out) {
  __shared__ float red[256][19];
  int t = threadIdx.x;
  int lane = t & 63;
  int kq = __builtin_amdgcn_readfirstlane(t >> 6);   // wave-uniform K quarter
  int p = blockIdx.x * 64 + lane;
  int b = p >> 12, h = (p >> 6) & 63, w = p & 63;
  float acc[18] = {};
  for (int kc = kq * 36; kc < kq * 36 + 36; ++kc) {
    int k0 = kc * 16;
    int tap = k0 >> 8, c0 = k0 & 255;
    int y = h + tap / 3 - 1, xx = w + tap % 3 - 1;
    float a[16];
#pragma unroll
    for (int q = 0; q < 16; ++q) a[q] = 0.f;
    if ((unsigned)y < 64u && (unsigned)xx < 64u) {
      const float4* srcp =
          (const float4*)(feat + ((b * 64 + y) * 64 + xx) * 256 + c0);
#pragma unroll
      for (int q = 0; q < 4; ++q) {
        float4 v = srcp[q];
        a[q * 4 + 0] = v.x; a[q * 4 + 1] = v.y;
        a[q * 4 + 2] = v.z; a[q * 4 + 3] = v.w;
      }
    }
    const float* wp = wo + k0 * 18;   // wave-uniform -> scalar loads
#pragma unroll
    for (int kk = 0; kk < 16; ++kk)
#pragma unroll
      for (int o = 0; o < 18; ++o)
        acc[o] += a[kk] * wp[kk * 18 + o];
  }
#pragma unroll
  for (int o = 0; o < 18; ++o) red[t][o] = acc[o];
  __syncthreads();
  if (kq == 0) {
#pragma unroll
    for (int o = 0; o < 18; ++o) {
      float s = red[lane][o] + red[lane + 64][o] + red[lane + 128][o] +
                red[lane + 192][o];
      if (NCHW)
        out[(b * 18 + o) * 4096 + (p & 4095)] = s;
      else
        out[p * 18 + o] = s;
    }
  }
}

// ---------------- deform conv as fused-gather GEMM ----------------
// M=16384 px, N=256 oc, K=2304. Block: BM=64 px x BN=64 oc, 256 threads,
// BK=16 (one tap x 16 channels per chunk). A gathered bilinearly from NHWC feat.
__global__ __launch_bounds__(256) void deform_gemm(const float* __restrict__ feat,
                                                   const float* __restrict__ off,
                                                   const float* __restrict__ wt,
                                                   float* __restrict__ out) {
  __shared__ __align__(16) float As[64][20];   // [m][kk], padded
  __shared__ __align__(16) float Bs[16][64];   // [kk][n]
  __shared__ float cy[9][64], cx[9][64];
  int t = threadIdx.x;
  int pbase = blockIdx.x * 64, n0 = blockIdx.y * 64;
  int b = pbase >> 12, h = (pbase >> 6) & 63;  // block-uniform

  // precompute sampling coords per (tap, pixel)
  {
    int m = t & 63;
    int p = pbase + m;
    for (int tap = t >> 6; tap < 9; tap += 4) {
      float dy = off[p * 18 + 2 * tap];
      float dx = off[p * 18 + 2 * tap + 1];
      cy[tap][m] = dy + (float)(tap / 3 - 1 + h);
      cx[tap][m] = dx + (float)(tap % 3 - 1 + m);
    }
  }
  __syncthreads();

  float acc[4][4] = {};
  int tm = t >> 4, tn = t & 15;   // compute mapping
  int jj = t & 3, m = t >> 2;     // A-load mapping (4 ch per thread)
  int bkk = t >> 4, bn4 = t & 15; // B-load mapping

  const float* fbase = feat + b * 4096 * 256;

  for (int kc = 0; kc < 144; ++kc) {
    int k0 = kc * 16;
    int tap = k0 >> 8, c0 = k0 & 255;

    // ---- gather A fragment (4 channels at this thread's pixel/tap) ----
    float py = cy[tap][m], px = cx[tap][m];
    float fy = floorf(py), fx = floorf(px);
    int iy = (int)fy, ix = (int)fx;
    float wy1 = py - fy, wy0 = 1.f - wy1;
    float wx1 = px - fx, wx0 = 1.f - wx1;
    float4 v = {0.f, 0.f, 0.f, 0.f};
    const float* fp = fbase + c0 + jj * 4;
    {
      float wgt = wy0 * wx0;
      if ((unsigned)iy < 64u && (unsigned)ix < 64u) {
        float4 c = *(const float4*)(fp + (iy * 64 + ix) * 256);
        v.x += wgt * c.x; v.y += wgt * c.y; v.z += wgt * c.z; v.w += wgt * c.w;
      }
    }
    {
      float wgt = wy0 * wx1;
      if ((unsigned)iy < 64u && (unsigned)(ix + 1) < 64u) {
        float4 c = *(const float4*)(fp + (iy * 64 + ix + 1) * 256);
        v.x += wgt * c.x; v.y += wgt * c.y; v.z += wgt * c.z; v.w += wgt * c.w;
      }
    }
    {
      float wgt = wy1 * wx0;
      if ((unsigned)(iy + 1) < 64u && (unsigned)ix < 64u) {
        float4 c = *(const float4*)(fp + ((iy + 1) * 64 + ix) * 256);
        v.x += wgt * c.x; v.y += wgt * c.y; v.z += wgt * c.z; v.w += wgt * c.w;
      }
    }
    {
      float wgt = wy1 * wx1;
      if ((unsigned)(iy + 1) < 64u && (unsigned)(ix + 1) < 64u) {
        float4 c = *(const float4*)(fp + ((iy + 1) * 64 + ix + 1) * 256);
        v.x += wgt * c.x; v.y += wgt * c.y; v.z += wgt * c.z; v.w += wgt * c.w;
      }
    }

    // ---- B fragment ----
    float4 bv = *(const float4*)(wt + (k0 + bkk) * 256 + n0 + bn4 * 4);

    __syncthreads();   // previous chunk's LDS reads done
    *(float4*)&As[m][jj * 4] = v;
    *(float4*)&Bs[bkk][bn4 * 4] = bv;
    __syncthreads();

#pragma unroll
    for (int kk = 0; kk < 16; ++kk) {
      float4 b4 = *(const float4*)&Bs[kk][tn * 4];
#pragma unroll
      for (int r = 0; r < 4; ++r) {
        float a = As[tm * 4 + r][kk];
        acc[r][0] += a * b4.x;
        acc[r][1] += a * b4.y;
        acc[r][2] += a * b4.z;
        acc[r][3] += a * b4.w;
      }
    }
  }

  // epilogue: NHWC store
#pragma unroll
  for (int r = 0; r < 4; ++r) {
    int p = pbase + tm * 4 + r;
    float4 o4 = {acc[r][0], acc[r][1], acc[r][2], acc[r][3]};
    *(float4*)&out[p * 256 + n0 + tn * 4] = o4;
  }
}

// ---------------- launcher ----------------
extern "C" void kernel_launch(void* const* d_in, const int* in_sizes, int n_in,
                              void* d_out, int out_size, void* d_ws, size_t ws_size,
                              hipStream_t stream) {
  const float* x  = (const float*)d_in[0];
  const float* y  = (const float*)d_in[1];
  const float* ow = (const float*)d_in[2];   // [4][18][256][3][3]
  const float* dw = (const float*)d_in[3];   // [3][256][256][3][3]
  float* out = (float*)d_out;

  float* fA      = (float*)d_ws;
  float* fB      = fA + FEAT_N;
  float* off_buf = fB + FEAT_N;
  float* wt      = off_buf + OFF_N;          // 3 * WT_L
  float* wto     = wt + 3 * WT_L;            // 4 * WTO_L
  // total ~42.5 MB of ws

  concat_nhwc<<<dim3(1024), dim3(256), 0, stream>>>(x, y, fA);
  t_dw<<<dim3(3 * WT_L / 256), dim3(256), 0, stream>>>(dw, wt);
  t_ow<<<dim3(4 * WTO_L / 256), dim3(256), 0, stream>>>(ow, wto);

  float* cur = fA;
  float* nxt = fB;
  for (int i = 0; i < 3; ++i) {
    off_conv<false><<<dim3(256), dim3(256), 0, stream>>>(cur, wto + i * WTO_L,
                                                         off_buf);
    deform_gemm<<<dim3(256, 4), dim3(256), 0, stream>>>(cur, off_buf,
                                                        wt + i * WT_L, nxt);
    float* tmp = cur; cur = nxt; nxt = tmp;
  }
  off_conv<true><<<dim3(256), dim3(256), 0, stream>>>(cur, wto + 3 * WTO_L, out);
}